// Round 11
// baseline (156.510 us; speedup 1.0000x reference)
//
#include <hip/hip_runtime.h>

// B=8, S=1024, H=128, rel rows R=129. All inputs/outputs are float32.
constexpr int Bn = 8, Sn = 1024, Hn = 128, Rn = 129;
constexpr float INV_SCALE = 0.088388347648318447f; // 1/sqrt(128)
constexpr size_t YEL = (size_t)Bn * Sn * Hn;       // y output elements

typedef short bf16x8 __attribute__((ext_vector_type(8)));
typedef short v4s __attribute__((ext_vector_type(4)));
typedef float f32x4 __attribute__((ext_vector_type(4)));
typedef int v4i __attribute__((ext_vector_type(4)));

__device__ __forceinline__ float bf2f(short s) {
    unsigned u = ((unsigned)(unsigned short)s) << 16;
    float f; __builtin_memcpy(&f, &u, 4); return f;
}
__device__ __forceinline__ short f2bf(float f) {
    unsigned u; __builtin_memcpy(&u, &f, 4);
    unsigned r = (u + 0x7fffu + ((u >> 16) & 1u)) >> 16;
    return (short)(r & 0xffffu);
}

// Async 16B global -> LDS (direct-to-LDS DMA; dest = wave-uniform base + lane*16).
__device__ __forceinline__ void gll16(const short* g, short* l) {
    __builtin_amdgcn_global_load_lds(
        (const __attribute__((address_space(1))) void*)g,
        (__attribute__((address_space(3))) void*)l, 16, 0, 0);
}

// Merged table builder:
//   blocks [0, Rn):            relcat[p] = [rh(128) | rh(128) | rl(128)]
//   blocks [Rn, Rn+107):       BcatT[n][k] (ld 320)
//   blocks [Rn+107, Rn+235):   wtab: transposed hi/lo bf16 weights for proj
__global__ __launch_bounds__(384) void build_tables(
    const float* __restrict__ rel_k, const float* __restrict__ rel_v,
    const float* __restrict__ Wo,
    const float* __restrict__ Wq, const float* __restrict__ Wk,
    const float* __restrict__ Wv,
    short* __restrict__ relcat, short* __restrict__ BcatT,
    short* __restrict__ wtab)
{
    if (blockIdx.x < Rn) {
        const int p = blockIdx.x, c = threadIdx.x;
        const int j = (c < 256) ? (c & 127) : (c - 256);
        float v = rel_k[p * Hn + j];
        short h = f2bf(v);
        relcat[p * 384 + c] = (c < 256) ? h : f2bf(v - bf2f(h));
    } else if (blockIdx.x < Rn + 107) {
        int idx = (blockIdx.x - Rn) * 384 + threadIdx.x;   // 0..40959 (320x128)
        if (idx < 320 * 128) {
            int k = idx >> 7, n = idx & 127;
            float v;
            if (k < 128) v = Wo[k * Hn + n];
            else if (k < 257) {
                int p = k - 128; float a = 0.f;
                for (int h = 0; h < Hn; ++h) a += rel_v[p * Hn + h] * Wo[h * Hn + n];
                v = a;
            } else v = 0.f;
            BcatT[n * 320 + k] = f2bf(v);
        }
    } else {
        int idx = (blockIdx.x - Rn - 107) * 384 + threadIdx.x;
        int sel = idx >> 14, rem = idx & 16383;
        int n = rem >> 7, k = rem & 127;
        const float* W = (sel == 0) ? Wq : (sel == 1) ? Wk : Wv;
        float v = W[k * Hn + n];
        short h = f2bf(v);
        wtab[sel * 32768 + n * 128 + k] = h;
        wtab[sel * 32768 + 16384 + n * 128 + k] = f2bf(v - bf2f(h));
    }
}

// MFMA projections: q = xh@wh + xh@wl + xl@wh (xl@wl dropped, ~1.5e-4).
__global__ __launch_bounds__(256) void proj(
    const float* __restrict__ X, const short* __restrict__ wtab,
    const float* __restrict__ bq, const float* __restrict__ bk,
    const float* __restrict__ bv,
    short* __restrict__ qcat, short* __restrict__ kh, short* __restrict__ vT)
{
    __shared__ float xs[64][128];
    const int tid = threadIdx.x;
    const int sel = blockIdx.y;
    const int row0 = blockIdx.x * 64;
    const float* bias = (sel == 0) ? bq : (sel == 1) ? bk : bv;
    const short* wh = wtab + sel * 32768;
    const short* wl = wh + 16384;

#pragma unroll
    for (int it = 0; it < 8; ++it) {
        int u = tid + it * 256;
        int r = u >> 5, c4 = (u & 31) * 4;
        *(float4*)&xs[r][c4] = *(const float4*)(X + (size_t)(row0 + r) * 128 + c4);
    }
    __syncthreads();

    const int w = tid >> 6, lane = tid & 63;
    const int quad = lane >> 4, l15 = lane & 15;

    bf16x8 xh[4], xl[4];
#pragma unroll
    for (int kk = 0; kk < 4; ++kk) {
#pragma unroll
        for (int j = 0; j < 8; ++j) {
            float v = xs[w * 16 + l15][kk * 32 + quad * 8 + j];
            short h = f2bf(v);
            xh[kk][j] = h;
            xl[kk][j] = f2bf(v - bf2f(h));
        }
    }

    f32x4 acc[8] = {};
#pragma unroll
    for (int nt = 0; nt < 8; ++nt) {
        const short* bh = wh + (size_t)(nt * 16 + l15) * 128;
        const short* bl = wl + (size_t)(nt * 16 + l15) * 128;
#pragma unroll
        for (int kk = 0; kk < 4; ++kk) {
            bf16x8 bhf = *(const bf16x8*)(bh + kk * 32 + quad * 8);
            bf16x8 blf = *(const bf16x8*)(bl + kk * 32 + quad * 8);
            acc[nt] = __builtin_amdgcn_mfma_f32_16x16x32_bf16(xh[kk], bhf, acc[nt], 0, 0, 0);
            acc[nt] = __builtin_amdgcn_mfma_f32_16x16x32_bf16(xh[kk], blf, acc[nt], 0, 0, 0);
            acc[nt] = __builtin_amdgcn_mfma_f32_16x16x32_bf16(xl[kk], bhf, acc[nt], 0, 0, 0);
        }
    }

#pragma unroll
    for (int nt = 0; nt < 8; ++nt) {
        int col = nt * 16 + l15;
        float bv2 = bias[col];
#pragma unroll
        for (int r = 0; r < 4; ++r) {
            int row = row0 + w * 16 + quad * 4 + r;
            float v = acc[nt][r] + bv2;
            short h = f2bf(v);
            if (sel == 0) {
                qcat[(size_t)row * 256 + col] = h;
                qcat[(size_t)row * 256 + 128 + col] = f2bf(v - bf2f(h));
            } else if (sel == 1) {
                kh[(size_t)row * 128 + col] = h;
            } else {
                int b = row >> 10, i = row & (Sn - 1);
                vT[(size_t)b * 131072 + (size_t)col * 1024 + i] = h;
            }
        }
    }
}

// Fully fused kernel, v8: m201-faithful counted-vmcnt pipeline.
// bufS = 4 quarter-buffers x 8 KB (same 32 KB). Round r: issue stage(r+2),
// `s_waitcnt vmcnt(2)` (stage r complete — it has >=2 younger ops; in-order
// retirement), RAW s_barrier (no drain!), read + 1 MFMA. Per-wave counted
// wait + barrier => all waves' stage(r) writes complete before any read —
// the cross-wave guarantee r9 lacked. Per-round full vmcnt(0) drains
// (~300-500cy x 64) become mostly-hidden counted waits. Quarter swizzle:
// chunk ^= (row>>1)&3 on BOTH source and read (<=2-way banks, free).
// attn NT stores moved to kernel END so stores never sit inside counted
// vmcnt waits (stores increment vmcnt).
__global__ __launch_bounds__(512, 4) void fused_attn(
    const short* __restrict__ qcat, const short* __restrict__ kh,
    const short* __restrict__ vT, const short* __restrict__ relcat,
    const short* __restrict__ BcatT,
    const float* __restrict__ X, const float* __restrict__ bo,
    const float* __restrict__ gamma, const float* __restrict__ beta,
    float* __restrict__ attn_g, float* __restrict__ y_g)
{
    __shared__ __align__(16) char smem[78848];
    short* bufS = (short*)smem;               // 32,768 B: 4 x 8 KB quarter-bufs
    short* Pb   = (short*)(smem + 32768);     // [16][1032] bf16 P      (33,024 B)
    short* CtxA = (short*)(smem + 65792);     // [16][344]  [ctx|arel]  (11,008 B)
    float* QrL  = (float*)(smem + 65792);     // [16][132] overlays CtxA (dead before it)
    float* redM = (float*)(smem + 76800);     // 4x [16][8] reduction arrays
    float* redS = redM + 128;
    float* redL = redS + 128;
    float* redH = redL + 128;

    const int tid = threadIdx.x;
    const int w = tid >> 6, lane = tid & 63;
    const int quad = lane >> 4, l15 = lane & 15;
    // XCD batch-affinity swizzle (bijective: 512 % 8 == 0).
    const int lb = blockIdx.x + (blockIdx.z << 6);   // 0..511
    const int bz = lb & 7;
    const int row0 = (lb >> 3) << 4;
    const size_t grow0 = (size_t)bz * Sn + row0;

    const short* khb  = kh + (size_t)bz * Sn * 128;
    const short* vtb0 = vT + (size_t)bz * 131072;

    // Quarter-tile staging: 128 rows x 32 shorts (8 KB), exactly 1 gll16/thread.
    // LDS[r'][c] = global[r'][c ^ ((r'>>1)&3)] (16B chunks c=0..3); dest is
    // lane-linear (tid*16 B) => wave-uniform base + lane*16 as HW requires.
    auto stage_khq = [&](int j) {
        int t = j >> 2, q = j & 3;
        int rr = tid >> 2, c = tid & 3;
        gll16(khb + (size_t)(t * 128 + rr) * 128 + q * 32 + ((c ^ ((rr >> 1) & 3)) * 8),
              bufS + (j & 3) * 4096 + tid * 8);
    };
    auto stage_vq = [&](int j) {
        int t = j >> 2, q = j & 3;
        int rr = tid >> 2, c = tid & 3;
        gll16(vtb0 + (size_t)rr * 1024 + t * 128 + q * 32 + ((c ^ ((rr >> 1) & 3)) * 8),
              bufS + (j & 3) * 4096 + tid * 8);
    };

    // prime the pipeline; prologue __syncthreads drains both (vmcnt(0)).
    stage_khq(0);
    stage_khq(1);

    // A-frags: q strip rows from qcat hi half (one-time per-lane loads)
    bf16x8 afr[4];
#pragma unroll
    for (int kk = 0; kk < 4; ++kk)
        afr[kk] = *(const bf16x8*)(qcat + (grow0 + l15) * 256 + kk * 32 + quad * 8);

    // ---- merged qrel prologue: QrL[lr][p] = q_f32(lr) . rel_k(p)
    {
        const short* aq = qcat + (grow0 + l15) * 256;
        const short* br = relcat + (size_t)(w * 16 + l15) * 384;
        const short* br2 = relcat + (size_t)(128 + l15) * 384;  // wave 0 extra tile
        f32x4 qacc = {};
        f32x4 qacc2 = {};
#pragma unroll
        for (int ks = 0; ks < 12; ++ks) {
            int koff = ks * 32 + quad * 8;
            int srcc = (koff >= 256) ? koff - 256 : koff;
            bf16x8 qa = *(const bf16x8*)(aq + srcc);
            bf16x8 qb = *(const bf16x8*)(br + ks * 32 + quad * 8);
            qacc = __builtin_amdgcn_mfma_f32_16x16x32_bf16(qa, qb, qacc, 0, 0, 0);
            if (w == 0) {
                bf16x8 qb2 = *(const bf16x8*)(br2 + ks * 32 + quad * 8);
                qacc2 = __builtin_amdgcn_mfma_f32_16x16x32_bf16(qa, qb2, qacc2, 0, 0, 0);
            }
        }
#pragma unroll
        for (int r = 0; r < 4; ++r)
            QrL[(quad * 4 + r) * 132 + w * 16 + l15] = qacc[r];
        if (w == 0 && l15 == 0) {
#pragma unroll
            for (int r = 0; r < 4; ++r)
                QrL[(quad * 4 + r) * 132 + 128] = qacc2[r];
        }
    }
    __syncthreads();   // QrL complete; stages 0,1 drained (full vmcnt(0))

    // ---- phase 1: scores — 32 quarter rounds, counted vmcnt + raw barriers
    const int rb = w * 16 + l15;
    const int jsw = quad ^ ((l15 >> 1) & 3);
    f32x4 acc[8] = {};
#pragma unroll
    for (int r = 0; r < 32; ++r) {
        if (r < 30) {
            stage_khq(r + 2);
            __builtin_amdgcn_sched_barrier(0);
            asm volatile("s_waitcnt vmcnt(2)" ::: "memory");
        } else if (r == 30) {
            asm volatile("s_waitcnt vmcnt(1)" ::: "memory");
        } else {
            asm volatile("s_waitcnt vmcnt(0)" ::: "memory");
        }
        __builtin_amdgcn_sched_barrier(0);
        __builtin_amdgcn_s_barrier();     // raw: no drain; all waves' stage(r) done
        __builtin_amdgcn_sched_barrier(0);
        const short* hb = bufS + (r & 3) * 4096;
        bf16x8 b = *(const bf16x8*)(hb + rb * 32 + jsw * 8);
        acc[r >> 2] = __builtin_amdgcn_mfma_f32_16x16x32_bf16(
            afr[r & 3], b, acc[r >> 2], 0, 0, 0);
    }

    // prime vT pipeline — drained by softmax's __syncthreads
    stage_vq(0);
    stage_vq(1);

    // ---- scale + qrel + row-max
    float mx[4];
#pragma unroll
    for (int r = 0; r < 4; ++r) {
        int lr = quad * 4 + r, i = row0 + lr;
        float m = -3.4e38f;
#pragma unroll
        for (int kt = 0; kt < 8; ++kt) {
            int col = kt * 128 + w * 16 + l15;
            int d = col - i; d = (d < -64) ? -64 : (d > 64 ? 64 : d);
            float v = acc[kt][r] * INV_SCALE + QrL[lr * 132 + d + 64];
            acc[kt][r] = v;
            m = fmaxf(m, v);
        }
#pragma unroll
        for (int msk = 1; msk < 16; msk <<= 1) m = fmaxf(m, __shfl_xor(m, msk));
        if (l15 == 0) redM[lr * 8 + w] = m;
    }
    __syncthreads();
#pragma unroll
    for (int r = 0; r < 4; ++r) {
        int lr = quad * 4 + r;
        float m = redM[lr * 8];
#pragma unroll
        for (int j = 1; j < 8; ++j) m = fmaxf(m, redM[lr * 8 + j]);
        mx[r] = m;
    }

    // ---- exp + partial sums (s, lo, hi)
#pragma unroll
    for (int r = 0; r < 4; ++r) {
        int lr = quad * 4 + r, i = row0 + lr;
        float s = 0.f, lo = 0.f, hi = 0.f;
#pragma unroll
        for (int kt = 0; kt < 8; ++kt) {
            float e = __expf(acc[kt][r] - mx[r]);
            acc[kt][r] = e;
            s += e;
            int col = kt * 128 + w * 16 + l15;
            lo += (col <= i - 64) ? e : 0.f;
            hi += (col >= i + 64) ? e : 0.f;
        }
#pragma unroll
        for (int msk = 1; msk < 16; msk <<= 1) {
            s += __shfl_xor(s, msk);
            lo += __shfl_xor(lo, msk);
            hi += __shfl_xor(hi, msk);
        }
        if (l15 == 0) { redS[lr * 8 + w] = s; redL[lr * 8 + w] = lo; redH[lr * 8 + w] = hi; }
    }
    __syncthreads();

    // ---- normalize into Pb (bf16)
#pragma unroll
    for (int r = 0; r < 4; ++r) {
        int lr = quad * 4 + r;
        float s = 0.f;
#pragma unroll
        for (int j = 0; j < 8; ++j) s += redS[lr * 8 + j];
        float inv = 1.0f / s;
#pragma unroll
        for (int kt = 0; kt < 8; ++kt) {
            int col = kt * 128 + w * 16 + l15;
            Pb[lr * 1032 + col] = f2bf(acc[kt][r] * inv);
        }
    }
    __syncthreads();   // Pb complete; v stages 0,1 drained (full vmcnt(0))

    // ---- phase 3: ctx = P @ V — 32 quarter rounds, counted vmcnt + raw barriers
    f32x4 cacc = {};
#pragma unroll
    for (int r = 0; r < 32; ++r) {
        if (r < 30) {
            stage_vq(r + 2);
            __builtin_amdgcn_sched_barrier(0);
            asm volatile("s_waitcnt vmcnt(2)" ::: "memory");
        } else if (r == 30) {
            asm volatile("s_waitcnt vmcnt(1)" ::: "memory");
        } else {
            asm volatile("s_waitcnt vmcnt(0)" ::: "memory");
        }
        __builtin_amdgcn_sched_barrier(0);
        __builtin_amdgcn_s_barrier();
        __builtin_amdgcn_sched_barrier(0);
        const short* hb = bufS + (r & 3) * 4096;
        bf16x8 a = *(const bf16x8*)&Pb[l15 * 1032 + r * 32 + quad * 8];
        bf16x8 b = *(const bf16x8*)(hb + rb * 32 + jsw * 8);
        cacc = __builtin_amdgcn_mfma_f32_16x16x32_bf16(a, b, cacc, 0, 0, 0);
    }

    // ---- build CtxA = [bf16(ctx) | arel(129) | 0] in LDS (overlays dead QrL)
#pragma unroll
    for (int r = 0; r < 4; ++r)
        CtxA[(quad * 4 + r) * 344 + w * 16 + l15] = f2bf(cacc[r]);
#pragma unroll
    for (int rr = 0; rr < 2; ++rr) {
        int lr = w * 2 + rr, i = row0 + lr;
        float s = 0.f, lo = 0.f, hi = 0.f;
#pragma unroll
        for (int j = 0; j < 8; ++j) {
            s += redS[lr * 8 + j]; lo += redL[lr * 8 + j]; hi += redH[lr * 8 + j];
        }
        float inv = 1.0f / s;
        float v0;
        if (lane == 0) v0 = lo * inv;
        else { int c = i + lane - 64; v0 = (c >= 0 && c < Sn) ? bf2f(Pb[lr * 1032 + c]) : 0.f; }
        CtxA[lr * 344 + 128 + lane] = f2bf(v0);
        int c1 = i + lane;
        CtxA[lr * 344 + 192 + lane] = (c1 < Sn) ? Pb[lr * 1032 + c1] : (short)0;
        CtxA[lr * 344 + 256 + lane] = (lane == 0) ? f2bf(hi * inv) : (short)0;
    }
    __syncthreads();

    // ---- phase 4: y = LN([ctx|arel] @ BcatT^T + bo + x), B direct from BcatT (L2-hot)
    f32x4 yacc = {};
    const short* bcb = BcatT + (size_t)(w * 16 + l15) * 320;
#pragma unroll
    for (int ch = 0; ch < 3; ++ch) {
        const int nkk = (ch == 2) ? 2 : 4;
#pragma unroll
        for (int kk = 0; kk < 4; ++kk) {
            if (kk >= nkk) break;
            bf16x8 a = *(const bf16x8*)&CtxA[l15 * 344 + ch * 128 + kk * 32 + quad * 8];
            bf16x8 b = *(const bf16x8*)(bcb + ch * 128 + kk * 32 + quad * 8);
            yacc = __builtin_amdgcn_mfma_f32_16x16x32_bf16(a, b, yacc, 0, 0, 0);
        }
    }

    // ---- residual + LayerNorm epilogue
    const int col = w * 16 + l15;
    const float bov = bo[col], gv = gamma[col], bev = beta[col];
    float vv[4];
#pragma unroll
    for (int r = 0; r < 4; ++r) {
        int lr = quad * 4 + r;
        vv[r] = yacc[r] + bov + X[(grow0 + lr) * 128 + col];
    }
#pragma unroll
    for (int r = 0; r < 4; ++r) {
        float s = vv[r];
#pragma unroll
        for (int msk = 1; msk < 16; msk <<= 1) s += __shfl_xor(s, msk);
        if (l15 == 0) redM[(quad * 4 + r) * 8 + w] = s;
    }
    __syncthreads();
    float mu[4];
#pragma unroll
    for (int r = 0; r < 4; ++r) {
        int lr = quad * 4 + r;
        float s = 0.f;
#pragma unroll
        for (int j = 0; j < 8; ++j) s += redM[lr * 8 + j];
        mu[r] = s * (1.f / 128.f);
    }
#pragma unroll
    for (int r = 0; r < 4; ++r) {
        float d = vv[r] - mu[r];
        float s = d * d;
#pragma unroll
        for (int msk = 1; msk < 16; msk <<= 1) s += __shfl_xor(s, msk);
        if (l15 == 0) redS[(quad * 4 + r) * 8 + w] = s;
    }
    __syncthreads();
#pragma unroll
    for (int r = 0; r < 4; ++r) {
        int lr = quad * 4 + r;
        float s = 0.f;
#pragma unroll
        for (int j = 0; j < 8; ++j) s += redS[lr * 8 + j];
        float inv = rsqrtf(s * (1.f / 128.f) + 1e-5f);
        float yv = (vv[r] - mu[r]) * inv * gv + bev;
        __builtin_nontemporal_store(yv, &y_g[(grow0 + lr) * 128 + col]);
    }

    // ---- attn f32 output LAST (Pb untouched since normalize; stores sit
    // outside all counted-vmcnt regions; kernel-end drain handles them).
    {
        float* ab = attn_g + grow0 * Sn;
#pragma unroll
        for (int it = 0; it < 8; ++it) {
            int u = tid + it * 512;            // 16 rows x 256 float4
            int r = u >> 8, c4 = (u & 255) * 4;
            v4s pv = *(const v4s*)&Pb[r * 1032 + c4];
            f32x4 o;
            o[0] = bf2f(pv[0]); o[1] = bf2f(pv[1]);
            o[2] = bf2f(pv[2]); o[3] = bf2f(pv[3]);
            __builtin_nontemporal_store(o, (f32x4*)(ab + (size_t)r * Sn + c4));
        }
    }
}

extern "C" void kernel_launch(void* const* d_in, const int* in_sizes, int n_in,
                              void* d_out, int out_size, void* d_ws, size_t ws_size,
                              hipStream_t stream) {
    const float* x     = (const float*)d_in[0];
    const float* Wq    = (const float*)d_in[1];
    const float* bq    = (const float*)d_in[2];
    const float* Wk    = (const float*)d_in[3];
    const float* bk    = (const float*)d_in[4];
    const float* Wv    = (const float*)d_in[5];
    const float* bv    = (const float*)d_in[6];
    const float* rel_k = (const float*)d_in[7];
    const float* rel_v = (const float*)d_in[8];
    const float* Wo    = (const float*)d_in[9];
    const float* bo    = (const float*)d_in[10];
    const float* gamma = (const float*)d_in[11];
    const float* beta  = (const float*)d_in[12];

    char* ws = (char*)d_ws;
    short* kh     = (short*)(ws + 0);          // 8x1024x128 bf16 (2 MB)
    short* vT     = (short*)(ws + 2097152);    // 8x128x1024 bf16 (2 MB)
    short* qcat   = (short*)(ws + 4194304);    // 8192x256 bf16 hi|lo (4 MB)
    short* relcat = (short*)(ws + 8388608);    // 129x384 bf16 in a padded 128 KB slot
    short* BcatT  = (short*)(ws + 8519680);    // 128x320 bf16 (80 KB + pad)
    short* wtab   = (short*)(ws + 8650752);    // 3 sels x (hi|lo) x 128x128 bf16 (192 KB)

    float* y_out = (float*)d_out;
    float* attn  = (float*)d_out + YEL;        // 8x1024x1024 f32

    build_tables<<<dim3(Rn + 107 + 128), 384, 0, stream>>>(
        rel_k, rel_v, Wo, Wq, Wk, Wv, relcat, BcatT, wtab);
    proj<<<dim3(128, 3), 256, 0, stream>>>(x, wtab, bq, bk, bv, qcat, kh, vT);

    fused_attn<<<dim3(64, 1, Bn), 512, 0, stream>>>(
        qcat, kh, vT, relcat, BcatT, x, bo, gamma, beta, attn, y_out);
}

// Round 12
// 153.702 us; speedup vs baseline: 1.0183x; 1.0183x over previous
//
#include <hip/hip_runtime.h>

// B=8, S=1024, H=128, rel rows R=129. All inputs/outputs are float32.
constexpr int Bn = 8, Sn = 1024, Hn = 128, Rn = 129;
constexpr float INV_SCALE = 0.088388347648318447f; // 1/sqrt(128)
constexpr size_t YEL = (size_t)Bn * Sn * Hn;       // y output elements

typedef short bf16x8 __attribute__((ext_vector_type(8)));
typedef short v4s __attribute__((ext_vector_type(4)));
typedef float f32x4 __attribute__((ext_vector_type(4)));
typedef int v4i __attribute__((ext_vector_type(4)));

__device__ __forceinline__ float bf2f(short s) {
    unsigned u = ((unsigned)(unsigned short)s) << 16;
    float f; __builtin_memcpy(&f, &u, 4); return f;
}
__device__ __forceinline__ short f2bf(float f) {
    unsigned u; __builtin_memcpy(&u, &f, 4);
    unsigned r = (u + 0x7fffu + ((u >> 16) & 1u)) >> 16;
    return (short)(r & 0xffffu);
}

// Async 16B global -> LDS (direct-to-LDS DMA; dest = wave-uniform base + lane*16).
__device__ __forceinline__ void gll16(const short* g, short* l) {
    __builtin_amdgcn_global_load_lds(
        (const __attribute__((address_space(1))) void*)g,
        (__attribute__((address_space(3))) void*)l, 16, 0, 0);
}

// Merged table builder:
//   blocks [0, Rn):            relcat[p] = [rh(128) | rh(128) | rl(128)]
//   blocks [Rn, Rn+107):       BcatT[n][k] (ld 320)
//   blocks [Rn+107, Rn+235):   wtab: transposed hi/lo bf16 weights for proj
__global__ __launch_bounds__(384) void build_tables(
    const float* __restrict__ rel_k, const float* __restrict__ rel_v,
    const float* __restrict__ Wo,
    const float* __restrict__ Wq, const float* __restrict__ Wk,
    const float* __restrict__ Wv,
    short* __restrict__ relcat, short* __restrict__ BcatT,
    short* __restrict__ wtab)
{
    if (blockIdx.x < Rn) {
        const int p = blockIdx.x, c = threadIdx.x;
        const int j = (c < 256) ? (c & 127) : (c - 256);
        float v = rel_k[p * Hn + j];
        short h = f2bf(v);
        relcat[p * 384 + c] = (c < 256) ? h : f2bf(v - bf2f(h));
    } else if (blockIdx.x < Rn + 107) {
        int idx = (blockIdx.x - Rn) * 384 + threadIdx.x;   // 0..40959 (320x128)
        if (idx < 320 * 128) {
            int k = idx >> 7, n = idx & 127;
            float v;
            if (k < 128) v = Wo[k * Hn + n];
            else if (k < 257) {
                int p = k - 128; float a = 0.f;
                for (int h = 0; h < Hn; ++h) a += rel_v[p * Hn + h] * Wo[h * Hn + n];
                v = a;
            } else v = 0.f;
            BcatT[n * 320 + k] = f2bf(v);
        }
    } else {
        int idx = (blockIdx.x - Rn - 107) * 384 + threadIdx.x;
        int sel = idx >> 14, rem = idx & 16383;
        int n = rem >> 7, k = rem & 127;
        const float* W = (sel == 0) ? Wq : (sel == 1) ? Wk : Wv;
        float v = W[k * Hn + n];
        short h = f2bf(v);
        wtab[sel * 32768 + n * 128 + k] = h;
        wtab[sel * 32768 + 16384 + n * 128 + k] = f2bf(v - bf2f(h));
    }
}

// MFMA projections: q = xh@wh + xh@wl + xl@wh (xl@wl dropped, ~1.5e-4).
__global__ __launch_bounds__(256) void proj(
    const float* __restrict__ X, const short* __restrict__ wtab,
    const float* __restrict__ bq, const float* __restrict__ bk,
    const float* __restrict__ bv,
    short* __restrict__ qcat, short* __restrict__ kh, short* __restrict__ vT)
{
    __shared__ float xs[64][128];
    const int tid = threadIdx.x;
    const int sel = blockIdx.y;
    const int row0 = blockIdx.x * 64;
    const float* bias = (sel == 0) ? bq : (sel == 1) ? bk : bv;
    const short* wh = wtab + sel * 32768;
    const short* wl = wh + 16384;

#pragma unroll
    for (int it = 0; it < 8; ++it) {
        int u = tid + it * 256;
        int r = u >> 5, c4 = (u & 31) * 4;
        *(float4*)&xs[r][c4] = *(const float4*)(X + (size_t)(row0 + r) * 128 + c4);
    }
    __syncthreads();

    const int w = tid >> 6, lane = tid & 63;
    const int quad = lane >> 4, l15 = lane & 15;

    bf16x8 xh[4], xl[4];
#pragma unroll
    for (int kk = 0; kk < 4; ++kk) {
#pragma unroll
        for (int j = 0; j < 8; ++j) {
            float v = xs[w * 16 + l15][kk * 32 + quad * 8 + j];
            short h = f2bf(v);
            xh[kk][j] = h;
            xl[kk][j] = f2bf(v - bf2f(h));
        }
    }

    f32x4 acc[8] = {};
#pragma unroll
    for (int nt = 0; nt < 8; ++nt) {
        const short* bh = wh + (size_t)(nt * 16 + l15) * 128;
        const short* bl = wl + (size_t)(nt * 16 + l15) * 128;
#pragma unroll
        for (int kk = 0; kk < 4; ++kk) {
            bf16x8 bhf = *(const bf16x8*)(bh + kk * 32 + quad * 8);
            bf16x8 blf = *(const bf16x8*)(bl + kk * 32 + quad * 8);
            acc[nt] = __builtin_amdgcn_mfma_f32_16x16x32_bf16(xh[kk], bhf, acc[nt], 0, 0, 0);
            acc[nt] = __builtin_amdgcn_mfma_f32_16x16x32_bf16(xh[kk], blf, acc[nt], 0, 0, 0);
            acc[nt] = __builtin_amdgcn_mfma_f32_16x16x32_bf16(xl[kk], bhf, acc[nt], 0, 0, 0);
        }
    }

#pragma unroll
    for (int nt = 0; nt < 8; ++nt) {
        int col = nt * 16 + l15;
        float bv2 = bias[col];
#pragma unroll
        for (int r = 0; r < 4; ++r) {
            int row = row0 + w * 16 + quad * 4 + r;
            float v = acc[nt][r] + bv2;
            short h = f2bf(v);
            if (sel == 0) {
                qcat[(size_t)row * 256 + col] = h;
                qcat[(size_t)row * 256 + 128 + col] = f2bf(v - bf2f(h));
            } else if (sel == 1) {
                kh[(size_t)row * 128 + col] = h;
            } else {
                int b = row >> 10, i = row & (Sn - 1);
                vT[(size_t)b * 131072 + (size_t)col * 1024 + i] = h;
            }
        }
    }
}

// Fully fused: qrel (merged) + scores + softmax + attn-write + P@V +
// [ctx|arel]@BcatT + residual + LayerNorm -> y.
// Verified-best structure (r8/r10, 153.7-155.8 us total): block-wide async
// gll16 double-buffered staging with __syncthreads per round. Session
// evidence: destage (r1), reg-prefetch (r3), NT stores (r6), counted-vmcnt
// pipeline (r11) all land at 43-47 us — this decomposition's floor is
// latency-structural, not staging-sync-bound.
__global__ __launch_bounds__(512, 4) void fused_attn(
    const short* __restrict__ qcat, const short* __restrict__ kh,
    const short* __restrict__ vT, const short* __restrict__ relcat,
    const short* __restrict__ BcatT,
    const float* __restrict__ X, const float* __restrict__ bo,
    const float* __restrict__ gamma, const float* __restrict__ beta,
    float* __restrict__ attn_g, float* __restrict__ y_g)
{
    __shared__ __align__(16) char smem[78848];
    short* bufS = (short*)smem;               // 32,768 B: 2 x 16,384 halves
    short* Pb   = (short*)(smem + 32768);     // [16][1032] bf16 P      (33,024 B)
    short* CtxA = (short*)(smem + 65792);     // [16][344]  [ctx|arel]  (11,008 B)
    float* QrL  = (float*)(smem + 65792);     // [16][132] overlays CtxA (dead before it)
    float* redM = (float*)(smem + 76800);     // 4x [16][8] reduction arrays
    float* redS = redM + 128;
    float* redL = redS + 128;
    float* redH = redL + 128;

    const int tid = threadIdx.x;
    const int w = tid >> 6, lane = tid & 63;
    const int quad = lane >> 4, l15 = lane & 15;
    // XCD batch-affinity swizzle (bijective: 512 % 8 == 0).
    const int lb = blockIdx.x + (blockIdx.z << 6);   // 0..511
    const int bz = lb & 7;
    const int row0 = (lb >> 3) << 4;
    const size_t grow0 = (size_t)bz * Sn + row0;

    const short* khb  = kh + (size_t)bz * Sn * 128;
    const short* vtb0 = vT + (size_t)bz * 131072;

    auto stage_kh = [&](int kt2) {
        const short* base = khb + (size_t)((kt2 >> 1) * 128) * 128 + (kt2 & 1) * 64;
        short* dst = bufS + (kt2 & 1) * 8192;
#pragma unroll
        for (int it = 0; it < 2; ++it) {
            int g = tid + it * 512;
            int r = g >> 3, c = g & 7;
            gll16(base + r * 128 + ((c ^ (r & 7)) * 8), dst + g * 8);
        }
    };
    auto stage_v = [&](int kc2) {
        const short* base = vtb0 + (kc2 >> 1) * 128 + (kc2 & 1) * 64;
        short* dst = bufS + (kc2 & 1) * 8192;
#pragma unroll
        for (int it = 0; it < 2; ++it) {
            int g = tid + it * 512;
            int r = g >> 3, c = g & 7;
            gll16(base + r * 1024 + ((c ^ (r & 7)) * 8), dst + g * 8);
        }
    };

    // issue first kh half-tile now; the qrel prologue below hides its latency
    stage_kh(0);

    // A-frags: q strip rows from qcat hi half (one-time per-lane loads)
    bf16x8 afr[4];
#pragma unroll
    for (int kk = 0; kk < 4; ++kk)
        afr[kk] = *(const bf16x8*)(qcat + (grow0 + l15) * 256 + kk * 32 + quad * 8);

    // ---- merged qrel prologue: QrL[lr][p] = q_f32(lr) . rel_k(p)
    {
        const short* aq = qcat + (grow0 + l15) * 256;
        const short* br = relcat + (size_t)(w * 16 + l15) * 384;
        const short* br2 = relcat + (size_t)(128 + l15) * 384;  // wave 0 extra tile
        f32x4 qacc = {};
        f32x4 qacc2 = {};
#pragma unroll
        for (int ks = 0; ks < 12; ++ks) {
            int koff = ks * 32 + quad * 8;
            int srcc = (koff >= 256) ? koff - 256 : koff;
            bf16x8 qa = *(const bf16x8*)(aq + srcc);
            bf16x8 qb = *(const bf16x8*)(br + ks * 32 + quad * 8);
            qacc = __builtin_amdgcn_mfma_f32_16x16x32_bf16(qa, qb, qacc, 0, 0, 0);
            if (w == 0) {
                bf16x8 qb2 = *(const bf16x8*)(br2 + ks * 32 + quad * 8);
                qacc2 = __builtin_amdgcn_mfma_f32_16x16x32_bf16(qa, qb2, qacc2, 0, 0, 0);
            }
        }
#pragma unroll
        for (int r = 0; r < 4; ++r)
            QrL[(quad * 4 + r) * 132 + w * 16 + l15] = qacc[r];
        if (w == 0 && l15 == 0) {
#pragma unroll
            for (int r = 0; r < 4; ++r)
                QrL[(quad * 4 + r) * 132 + 128] = qacc2[r];
        }
    }
    __syncthreads();   // QrL complete; stage_kh(0) drained

    // ---- phase 1: scores, 16 dbuf'd half-tile rounds
    f32x4 acc[8] = {};
#pragma unroll
    for (int kt2 = 0; kt2 < 16; ++kt2) {
        if (kt2 < 15) stage_kh(kt2 + 1);     // issue BEFORE compute (T3-min)
        const short* hb = bufS + (kt2 & 1) * 8192;
        const int rb = w * 16 + l15;
#pragma unroll
        for (int kk = 0; kk < 2; ++kk) {
            int j = (kk * 4 + quad) ^ (l15 & 7);
            bf16x8 b = *(const bf16x8*)(hb + rb * 64 + j * 8);
            acc[kt2 >> 1] = __builtin_amdgcn_mfma_f32_16x16x32_bf16(
                afr[(kt2 & 1) * 2 + kk], b, acc[kt2 >> 1], 0, 0, 0);
        }
        __syncthreads();   // drains stage(kt2+1); protects next overwrite
    }

    // issue first vT half now — drained by softmax's own barriers
    stage_v(0);

    // ---- scale + qrel + row-max
    float mx[4];
#pragma unroll
    for (int r = 0; r < 4; ++r) {
        int lr = quad * 4 + r, i = row0 + lr;
        float m = -3.4e38f;
#pragma unroll
        for (int kt = 0; kt < 8; ++kt) {
            int col = kt * 128 + w * 16 + l15;
            int d = col - i; d = (d < -64) ? -64 : (d > 64 ? 64 : d);
            float v = acc[kt][r] * INV_SCALE + QrL[lr * 132 + d + 64];
            acc[kt][r] = v;
            m = fmaxf(m, v);
        }
#pragma unroll
        for (int msk = 1; msk < 16; msk <<= 1) m = fmaxf(m, __shfl_xor(m, msk));
        if (l15 == 0) redM[lr * 8 + w] = m;
    }
    __syncthreads();
#pragma unroll
    for (int r = 0; r < 4; ++r) {
        int lr = quad * 4 + r;
        float m = redM[lr * 8];
#pragma unroll
        for (int j = 1; j < 8; ++j) m = fmaxf(m, redM[lr * 8 + j]);
        mx[r] = m;
    }

    // ---- exp + partial sums (s, lo, hi)
#pragma unroll
    for (int r = 0; r < 4; ++r) {
        int lr = quad * 4 + r, i = row0 + lr;
        float s = 0.f, lo = 0.f, hi = 0.f;
#pragma unroll
        for (int kt = 0; kt < 8; ++kt) {
            float e = __expf(acc[kt][r] - mx[r]);
            acc[kt][r] = e;
            s += e;
            int col = kt * 128 + w * 16 + l15;
            lo += (col <= i - 64) ? e : 0.f;
            hi += (col >= i + 64) ? e : 0.f;
        }
#pragma unroll
        for (int msk = 1; msk < 16; msk <<= 1) {
            s += __shfl_xor(s, msk);
            lo += __shfl_xor(lo, msk);
            hi += __shfl_xor(hi, msk);
        }
        if (l15 == 0) { redS[lr * 8 + w] = s; redL[lr * 8 + w] = lo; redH[lr * 8 + w] = hi; }
    }
    __syncthreads();

    // ---- normalize into Pb (bf16)
#pragma unroll
    for (int r = 0; r < 4; ++r) {
        int lr = quad * 4 + r;
        float s = 0.f;
#pragma unroll
        for (int j = 0; j < 8; ++j) s += redS[lr * 8 + j];
        float inv = 1.0f / s;
#pragma unroll
        for (int kt = 0; kt < 8; ++kt) {
            int col = kt * 128 + w * 16 + l15;
            Pb[lr * 1032 + col] = f2bf(acc[kt][r] * inv);
        }
    }
    __syncthreads();   // Pb complete; stage_v(0) also drained by now

    // ---- attn f32 output: coalesced NON-TEMPORAL f32x4 stores from Pb
    {
        float* ab = attn_g + grow0 * Sn;
#pragma unroll
        for (int it = 0; it < 8; ++it) {
            int u = tid + it * 512;            // 16 rows x 256 float4
            int r = u >> 8, c4 = (u & 255) * 4;
            v4s pv = *(const v4s*)&Pb[r * 1032 + c4];
            f32x4 o;
            o[0] = bf2f(pv[0]); o[1] = bf2f(pv[1]);
            o[2] = bf2f(pv[2]); o[3] = bf2f(pv[3]);
            __builtin_nontemporal_store(o, (f32x4*)(ab + (size_t)r * Sn + c4));
        }
    }

    // ---- phase 3: ctx = P @ V, 16 dbuf'd vT half-tile rounds
    f32x4 cacc = {};
#pragma unroll
    for (int kc2 = 0; kc2 < 16; ++kc2) {
        if (kc2 < 15) stage_v(kc2 + 1);
        const short* hb = bufS + (kc2 & 1) * 8192;
        const int rb = w * 16 + l15;
#pragma unroll
        for (int kk = 0; kk < 2; ++kk) {
            bf16x8 a = *(const bf16x8*)&Pb[l15 * 1032 + kc2 * 64 + kk * 32 + quad * 8];
            int j = (kk * 4 + quad) ^ (l15 & 7);
            bf16x8 b = *(const bf16x8*)(hb + rb * 64 + j * 8);
            cacc = __builtin_amdgcn_mfma_f32_16x16x32_bf16(a, b, cacc, 0, 0, 0);
        }
        __syncthreads();
    }

    // ---- build CtxA = [bf16(ctx) | arel(129) | 0] in LDS (overlays dead QrL)
#pragma unroll
    for (int r = 0; r < 4; ++r)
        CtxA[(quad * 4 + r) * 344 + w * 16 + l15] = f2bf(cacc[r]);
#pragma unroll
    for (int rr = 0; rr < 2; ++rr) {
        int lr = w * 2 + rr, i = row0 + lr;
        float s = 0.f, lo = 0.f, hi = 0.f;
#pragma unroll
        for (int j = 0; j < 8; ++j) {
            s += redS[lr * 8 + j]; lo += redL[lr * 8 + j]; hi += redH[lr * 8 + j];
        }
        float inv = 1.0f / s;
        float v0;
        if (lane == 0) v0 = lo * inv;
        else { int c = i + lane - 64; v0 = (c >= 0 && c < Sn) ? bf2f(Pb[lr * 1032 + c]) : 0.f; }
        CtxA[lr * 344 + 128 + lane] = f2bf(v0);
        int c1 = i + lane;
        CtxA[lr * 344 + 192 + lane] = (c1 < Sn) ? Pb[lr * 1032 + c1] : (short)0;
        CtxA[lr * 344 + 256 + lane] = (lane == 0) ? f2bf(hi * inv) : (short)0;
    }
    __syncthreads();

    // ---- phase 4: y = LN([ctx|arel] @ BcatT^T + bo + x), B direct from BcatT (L2-hot)
    f32x4 yacc = {};
    const short* bcb = BcatT + (size_t)(w * 16 + l15) * 320;
#pragma unroll
    for (int ch = 0; ch < 3; ++ch) {
        const int nkk = (ch == 2) ? 2 : 4;
#pragma unroll
        for (int kk = 0; kk < 4; ++kk) {
            if (kk >= nkk) break;
            bf16x8 a = *(const bf16x8*)&CtxA[l15 * 344 + ch * 128 + kk * 32 + quad * 8];
            bf16x8 b = *(const bf16x8*)(bcb + ch * 128 + kk * 32 + quad * 8);
            yacc = __builtin_amdgcn_mfma_f32_16x16x32_bf16(a, b, yacc, 0, 0, 0);
        }
    }

    // ---- residual + LayerNorm epilogue
    const int col = w * 16 + l15;
    const float bov = bo[col], gv = gamma[col], bev = beta[col];
    float vv[4];
#pragma unroll
    for (int r = 0; r < 4; ++r) {
        int lr = quad * 4 + r;
        vv[r] = yacc[r] + bov + X[(grow0 + lr) * 128 + col];
    }
#pragma unroll
    for (int r = 0; r < 4; ++r) {
        float s = vv[r];
#pragma unroll
        for (int msk = 1; msk < 16; msk <<= 1) s += __shfl_xor(s, msk);
        if (l15 == 0) redM[(quad * 4 + r) * 8 + w] = s;
    }
    __syncthreads();
    float mu[4];
#pragma unroll
    for (int r = 0; r < 4; ++r) {
        int lr = quad * 4 + r;
        float s = 0.f;
#pragma unroll
        for (int j = 0; j < 8; ++j) s += redM[lr * 8 + j];
        mu[r] = s * (1.f / 128.f);
    }
#pragma unroll
    for (int r = 0; r < 4; ++r) {
        float d = vv[r] - mu[r];
        float s = d * d;
#pragma unroll
        for (int msk = 1; msk < 16; msk <<= 1) s += __shfl_xor(s, msk);
        if (l15 == 0) redS[(quad * 4 + r) * 8 + w] = s;
    }
    __syncthreads();
#pragma unroll
    for (int r = 0; r < 4; ++r) {
        int lr = quad * 4 + r;
        float s = 0.f;
#pragma unroll
        for (int j = 0; j < 8; ++j) s += redS[lr * 8 + j];
        float inv = rsqrtf(s * (1.f / 128.f) + 1e-5f);
        float yv = (vv[r] - mu[r]) * inv * gv + bev;
        __builtin_nontemporal_store(yv, &y_g[(grow0 + lr) * 128 + col]);
    }
}

extern "C" void kernel_launch(void* const* d_in, const int* in_sizes, int n_in,
                              void* d_out, int out_size, void* d_ws, size_t ws_size,
                              hipStream_t stream) {
    const float* x     = (const float*)d_in[0];
    const float* Wq    = (const float*)d_in[1];
    const float* bq    = (const float*)d_in[2];
    const float* Wk    = (const float*)d_in[3];
    const float* bk    = (const float*)d_in[4];
    const float* Wv    = (const float*)d_in[5];
    const float* bv    = (const float*)d_in[6];
    const float* rel_k = (const float*)d_in[7];
    const float* rel_v = (const float*)d_in[8];
    const float* Wo    = (const float*)d_in[9];
    const float* bo    = (const float*)d_in[10];
    const float* gamma = (const float*)d_in[11];
    const float* beta  = (const float*)d_in[12];

    char* ws = (char*)d_ws;
    short* kh     = (short*)(ws + 0);          // 8x1024x128 bf16 (2 MB)
    short* vT     = (short*)(ws + 2097152);    // 8x128x1024 bf16 (2 MB)
    short* qcat   = (short*)(ws + 4194304);    // 8192x256 bf16 hi|lo (4 MB)
    short* relcat = (short*)(ws + 8388608);    // 129x384 bf16 in a padded 128 KB slot
    short* BcatT  = (short*)(ws + 8519680);    // 128x320 bf16 (80 KB + pad)
    short* wtab   = (short*)(ws + 8650752);    // 3 sels x (hi|lo) x 128x128 bf16 (192 KB)

    float* y_out = (float*)d_out;
    float* attn  = (float*)d_out + YEL;        // 8x1024x1024 f32

    build_tables<<<dim3(Rn + 107 + 128), 384, 0, stream>>>(
        rel_k, rel_v, Wo, Wq, Wk, Wv, relcat, BcatT, wtab);
    proj<<<dim3(128, 3), 256, 0, stream>>>(x, wtab, bq, bk, bv, qcat, kh, vT);

    fused_attn<<<dim3(64, 1, Bn), 512, 0, stream>>>(
        qcat, kh, vT, relcat, BcatT, x, bo, gamma, beta, attn, y_out);
}